// Round 1
// 194.787 us; speedup vs baseline: 1.0059x; 1.0059x over previous
//
#include <hip/hip_runtime.h>
#include <hip/hip_bf16.h>
#include <cstdint>

#define DEVI __device__ __forceinline__

typedef __attribute__((ext_vector_type(8))) short bf16x8;
typedef __attribute__((ext_vector_type(4))) short bf16x4;
typedef __attribute__((ext_vector_type(4))) float f32x4;

template<int I> struct IC { static constexpr int v = I; };

DEVI short f2bf(float f) {
  unsigned u = __float_as_uint(f);
  u += 0x7fff + ((u >> 16) & 1);   // round-to-nearest-even
  return (short)(u >> 16);
}
DEVI float bf2f(short s) { return __uint_as_float(((unsigned)(unsigned short)s) << 16); }

DEVI void gl_lds16(const short* g, short* l) {
  __builtin_amdgcn_global_load_lds((const __attribute__((address_space(1))) unsigned*)g,
                                   (__attribute__((address_space(3))) unsigned*)l, 16, 0, 0);
}

DEVI void bar() {
  asm volatile("" ::: "memory");
  __builtin_amdgcn_s_barrier();
  asm volatile("" ::: "memory");
}

// ===========================================================================
// 256x256 GEMM: QK projection. R17: phases merged 4->2 per K-step.
// R16 counters: MfmaUtil 22.8%, VALUBusy 13%, HBM 13% -> sync/latency-bound;
// 8730 cyc/K-step vs 3295 for same structure at 4k^3 (m201). Per-phase fixed
// cost (~1350cy: 2 bars + lgkm drain) dominated the 621cy MFMA burst. Merging
// halves barrier count and doubles MFMA burst per phase. Stage issue order
// [B(ob1), A(s0)] [B(s0), A(s1)] preserved => vmcnt(6) drain semantics
// identical to R16 (oldest-8 at group end = next K-step's 4 slots).
// A-reads issued before B-reads: overwrite-hazard reads keep early queue slots.
// ===========================================================================
__global__ __launch_bounds__(512, 1)
void gemm_qkproj_8ph(const short* __restrict__ A, const short* __restrict__ B,
                     short* __restrict__ C, const float* __restrict__ b0,
                     const float* __restrict__ b1, float scale,
                     int K, int lda, int ldb, int ldc, int tilesN)
{
  const int nwg = gridDim.x, orig = blockIdx.x;
  const int q8 = nwg >> 3, r8 = nwg & 7;
  const int xcd = orig & 7, idx8 = orig >> 3;
  const int wg = (xcd < r8 ? xcd * (q8 + 1) : r8 * (q8 + 1) + (xcd - r8) * q8) + idx8;
  const int bi = wg / tilesN, bj = wg - bi * tilesN;

  __shared__ __align__(16) short lA[4][8192];
  __shared__ __align__(16) short lB[4][8192];

  const int tid = threadIdx.x, wave = tid >> 6, lane = tid & 63;
  const int wm = wave >> 2, wn = wave & 3;
  const int fr = lane & 15, h = lane >> 4;
  const int brow = bi * 256, bcol = bj * 256;

  const int ck = (h ^ ((fr >> 1) & 3)) * 8;
  const int aBase = (wm * 128 + fr) * 32 + ck;
  const int bBase = (wn * 64 + fr) * 32 + ck;

  const int swc = ((tid & 3) ^ ((tid >> 3) & 3)) * 8;
  const short* pa = A + (long long)(brow + (tid >> 2)) * lda + swc;
  const short* pb = B + (long long)(bcol + (tid >> 2)) * ldb + swc;

  f32x4 acc[8][4] = {};
  const int nt = K / 64;

  auto stgA = [&](auto SL, int koff) {
    constexpr int s = decltype(SL)::v;
    gl_lds16(pa + koff,                  &lA[s][tid * 8]);
    gl_lds16(pa + koff + 128 * (long long)lda, &lA[s][4096 + tid * 8]);
  };
  auto stgB = [&](auto SL, int koff) {
    constexpr int s = decltype(SL)::v;
    gl_lds16(pb + koff,                  &lB[s][tid * 8]);
    gl_lds16(pb + koff + 128 * (long long)ldb, &lB[s][4096 + tid * 8]);
  };

  stgA(IC<0>{}, 0);   stgB(IC<0>{}, 0);
  stgA(IC<1>{}, 32);  stgB(IC<1>{}, 32);
  stgA(IC<2>{}, 64);  stgB(IC<2>{}, 64);
  stgA(IC<3>{}, 96);
  asm volatile("s_waitcnt vmcnt(6)" ::: "memory");
  bar();

  auto group = [&](auto PC, int t) {
    constexpr int P  = decltype(PC)::v;
    constexpr int s0 = 2 * P, s1 = 2 * P + 1;
    constexpr int ob1 = 2 * (P ^ 1) + 1;
    const bool st1 = (t + 1 < nt), st2 = (t + 2 < nt);
    const int k2 = (t + 2) * 64;
    bf16x8 a[4], a2[4], b[4];

    // ---- merged phase A: K-half s0, both M-quadrants (32 MFMA) ----
#pragma unroll
    for (int m = 0; m < 4; ++m) a[m]  = *(const bf16x8*)&lA[s0][aBase + (m * 16) * 32];
#pragma unroll
    for (int m = 0; m < 4; ++m) a2[m] = *(const bf16x8*)&lA[s0][aBase + (64 + m * 16) * 32];
#pragma unroll
    for (int n = 0; n < 4; ++n) b[n]  = *(const bf16x8*)&lB[s0][bBase + (n * 16) * 32];
    if (st1) stgB(IC<ob1>{}, (t + 1) * 64 + 32);
    if (st2) stgA(IC<s0>{}, k2);
    bar();
    asm volatile("s_waitcnt lgkmcnt(0)" ::: "memory");
    __builtin_amdgcn_sched_barrier(0);
    __builtin_amdgcn_s_setprio(1);
#pragma unroll
    for (int m = 0; m < 4; ++m)
#pragma unroll
      for (int n = 0; n < 4; ++n)
        acc[m][n] = __builtin_amdgcn_mfma_f32_16x16x32_bf16(a[m], b[n], acc[m][n], 0, 0, 0);
#pragma unroll
    for (int m = 0; m < 4; ++m)
#pragma unroll
      for (int n = 0; n < 4; ++n)
        acc[m + 4][n] = __builtin_amdgcn_mfma_f32_16x16x32_bf16(a2[m], b[n], acc[m + 4][n], 0, 0, 0);
    __builtin_amdgcn_s_setprio(0);
    bar();

    // ---- merged phase B: K-half s1, both M-quadrants (32 MFMA) ----
#pragma unroll
    for (int m = 0; m < 4; ++m) a[m]  = *(const bf16x8*)&lA[s1][aBase + (m * 16) * 32];
#pragma unroll
    for (int m = 0; m < 4; ++m) a2[m] = *(const bf16x8*)&lA[s1][aBase + (64 + m * 16) * 32];
#pragma unroll
    for (int n = 0; n < 4; ++n) b[n]  = *(const bf16x8*)&lB[s1][bBase + (n * 16) * 32];
    if (st2) { stgB(IC<s0>{}, k2); stgA(IC<s1>{}, k2 + 32); }
    bar();
    asm volatile("s_waitcnt lgkmcnt(0)" ::: "memory");
    __builtin_amdgcn_sched_barrier(0);
    __builtin_amdgcn_s_setprio(1);
#pragma unroll
    for (int m = 0; m < 4; ++m)
#pragma unroll
      for (int n = 0; n < 4; ++n)
        acc[m][n] = __builtin_amdgcn_mfma_f32_16x16x32_bf16(a[m], b[n], acc[m][n], 0, 0, 0);
#pragma unroll
    for (int m = 0; m < 4; ++m)
#pragma unroll
      for (int n = 0; n < 4; ++n)
        acc[m + 4][n] = __builtin_amdgcn_mfma_f32_16x16x32_bf16(a2[m], b[n], acc[m + 4][n], 0, 0, 0);
    __builtin_amdgcn_s_setprio(0);
    if (st2)      asm volatile("s_waitcnt vmcnt(6)" ::: "memory");
    else if (st1) asm volatile("s_waitcnt vmcnt(0)" ::: "memory");
    if (st1) bar();
  };

  for (int t = 0; t + 1 < nt; t += 2) { group(IC<0>{}, t); group(IC<1>{}, t + 1); }

  // epilogue, n-INNERMOST: each 64B line completed within 4 consecutive stores
  int   colg[4]; float bvv[4], scl[4];
#pragma unroll
  for (int n = 0; n < 4; ++n) {
    colg[n] = bcol + wn * 64 + n * 16 + fr;
    const int seg = colg[n] >> 10;
    bvv[n] = seg ? b1[colg[n] & 1023] : b0[colg[n] & 1023];
    scl[n] = seg ? 1.f : scale;
  }
#pragma unroll
  for (int m = 0; m < 8; ++m) {
    const int row = brow + wm * 128 + m * 16 + h * 4;
#pragma unroll
    for (int j = 0; j < 4; ++j) {
      short* cr = C + (long long)(row + j) * ldc;
#pragma unroll
      for (int n = 0; n < 4; ++n)
        cr[colg[n]] = f2bf((acc[m][n][j] + bvv[n]) * scl[n]);
    }
  }
}

// ===========================================================================
// 128x128 GEMM, BK=64 (R15-proven). Epilogue reordered n-innermost (same
// write-amplification guard; matters for out-proj's 4MB/XCD fp32 C-tiles).
// DECODE 0 row-major / 2 row-major heavy-first (MODE 2).
// MODE 0 plain / 1 causal-QK skip / 2 causal-PV (kend=(bi+1)*128).
// BIASMODE 0 none / 1 col fp32.
// ===========================================================================
constexpr int BM = 128, BN = 128, BK = 64;

template<int MODE, int BIASMODE, bool OUTF32, int DECODE>
__global__ __launch_bounds__(256, 2)
void gemm_bt(const short* __restrict__ A, const short* __restrict__ B,
             void* __restrict__ Cv, const float* __restrict__ b0,
             float scale, int K, int lda, int ldb, int ldc,
             long long sA, long long sB, long long sC, int tdim)
{
  const int nwg = gridDim.x, orig = blockIdx.x;
  const int q8 = nwg >> 3, r8 = nwg & 7;
  const int xcd = orig & 7, idx8 = orig >> 3;
  const int wg = (xcd < r8 ? xcd * (q8 + 1) : r8 * (q8 + 1) + (xcd - r8) * q8) + idx8;
  int bi = wg / tdim;
  const int bj = wg - bi * tdim;
  if constexpr (DECODE == 2) bi = (nwg / tdim) - 1 - bi;   // heavy-first
  if (MODE == 1 && bj > bi) return;

  const int bz = blockIdx.z;
  A += (long long)bz * sA;
  B += (long long)bz * sB;

  __shared__ __align__(16) short lA[2][BM * BK];   // 2 x 16 KB
  __shared__ __align__(16) short lB[2][BN * BK];   // 2 x 16 KB

  const int tid = threadIdx.x, wave = tid >> 6, lane = tid & 63;
  const int wr = wave >> 1, wc = wave & 1;
  const int brow = bi * BM, bcol = bj * BN;
  const int fr = lane & 15, h = lane >> 4;

  const int ck0 = ((h ^ (fr & 7))) * 8;            // 128B-row swizzle, ks=0
  const int swc = ((tid & 7) ^ ((tid >> 3) & 7)) * 8;
  const short* pA = A + (long long)(brow + (tid >> 3)) * lda + swc;
  const short* pB = B + (long long)(bcol + (tid >> 3)) * ldb + swc;

  f32x4 acc[4][4] = {};
  const int kend = (MODE == 2) ? (bi + 1) * BM : K;
  const int nt = kend / BK;

  auto stage = [&](int buf, int t) {
    const long long ko = (long long)t * BK;
#pragma unroll
    for (int j = 0; j < 4; ++j)
      gl_lds16(pA + (long long)(j * 32) * lda + ko, &lA[buf][j * 2048 + tid * 8]);
#pragma unroll
    for (int j = 0; j < 4; ++j)
      gl_lds16(pB + (long long)(j * 32) * ldb + ko, &lB[buf][j * 2048 + tid * 8]);
  };

  stage(0, 0);
  __syncthreads();

  int cur = 0;
  for (int t = 0; t < nt; ++t) {
    if (t + 1 < nt) stage(cur ^ 1, t + 1);

    const short* bufA = lA[cur];
    const short* bufB = lB[cur];
    bf16x8 af[4], bg[4];
#pragma unroll
    for (int m = 0; m < 4; ++m)
      af[m] = *(const bf16x8*)&bufA[(wr * 64 + m * 16 + fr) * BK + ck0];
#pragma unroll
    for (int n = 0; n < 4; ++n)
      bg[n] = *(const bf16x8*)&bufB[(wc * 64 + n * 16 + fr) * BK + ck0];
#pragma unroll
    for (int m = 0; m < 4; ++m)
#pragma unroll
      for (int n = 0; n < 4; ++n)
        acc[m][n] = __builtin_amdgcn_mfma_f32_16x16x32_bf16(af[m], bg[n], acc[m][n], 0, 0, 0);
#pragma unroll
    for (int m = 0; m < 4; ++m)
      af[m] = *(const bf16x8*)&bufA[((wr * 64 + m * 16 + fr) * BK + ck0) ^ 32];
#pragma unroll
    for (int n = 0; n < 4; ++n)
      bg[n] = *(const bf16x8*)&bufB[((wc * 64 + n * 16 + fr) * BK + ck0) ^ 32];
#pragma unroll
    for (int m = 0; m < 4; ++m)
#pragma unroll
      for (int n = 0; n < 4; ++n)
        acc[m][n] = __builtin_amdgcn_mfma_f32_16x16x32_bf16(af[m], bg[n], acc[m][n], 0, 0, 0);

    __syncthreads();
    cur ^= 1;
  }

  // epilogue, n-innermost
  const int lrow = h * 4;
  float* Cf = (float*)Cv + (long long)bz * sC;
  short* Cs = (short*)Cv + (long long)bz * sC;
  int colg[4]; float bvv[4];
#pragma unroll
  for (int n = 0; n < 4; ++n) {
    colg[n] = bcol + wc * 64 + n * 16 + fr;
    bvv[n] = (BIASMODE == 1) ? b0[colg[n]] : 0.f;
  }
#pragma unroll
  for (int m = 0; m < 4; ++m) {
    const int row = brow + wr * 64 + m * 16 + lrow;
#pragma unroll
    for (int j = 0; j < 4; ++j) {
#pragma unroll
      for (int n = 0; n < 4; ++n) {
        const float val = (acc[m][n][j] + bvv[n]) * scale;
        if constexpr (OUTF32) Cf[(long long)(row + j) * ldc + colg[n]] = val;
        else                  Cs[(long long)(row + j) * ldc + colg[n]] = f2bf(val);
      }
    }
  }
}

// ---------------------------------------------------------------------------
// R17: causal trim. Row t has t+1 live cols; P@y (MODE 2) only reads cols
// < roundup128(t+1). Load only chunks with c0<=t; store only c0<wlim
// (keeps required zeros in the diagonal tile). Halves this kernel's traffic.
__global__ __launch_bounds__(256)
void softmax_causal_bf16_k(short* __restrict__ sc)
{
  const int T = 2048;
  const long long row = blockIdx.x;
  const int t = (int)(row & (T - 1));
  short* ps = sc + row * (long long)T;
  const int tid = threadIdx.x, wave = tid >> 6, lane = tid & 63;
  const int c0 = tid * 8;
  const int wlim = ((t >> 7) + 1) << 7;   // exclusive write limit, 128-aligned

  bf16x8 v = {};
  if (c0 <= t) v = *(const bf16x8*)&ps[c0];
  float x[8];
#pragma unroll
  for (int j = 0; j < 8; ++j) x[j] = bf2f(v[j]);

  float mx = -3.0e38f;
#pragma unroll
  for (int j = 0; j < 8; ++j) if (c0 + j <= t) mx = fmaxf(mx, x[j]);
#pragma unroll
  for (int o = 32; o; o >>= 1) mx = fmaxf(mx, __shfl_xor(mx, o, 64));
  __shared__ float red[8];
  if (lane == 0) red[wave] = mx;
  __syncthreads();
  const float M = fmaxf(fmaxf(red[0], red[1]), fmaxf(red[2], red[3]));

  float e[8], s = 0.f;
#pragma unroll
  for (int j = 0; j < 8; ++j) { e[j] = (c0 + j <= t) ? __expf(x[j] - M) : 0.f; s += e[j]; }
#pragma unroll
  for (int o = 32; o; o >>= 1) s += __shfl_xor(s, o, 64);
  if (lane == 0) red[4 + wave] = s;
  __syncthreads();
  const float inv = 1.f / (red[4] + red[5] + red[6] + red[7]);

  if (c0 < wlim) {
    bf16x8 ov;
#pragma unroll
    for (int j = 0; j < 8; ++j) ov[j] = f2bf(e[j] * inv);
    *(bf16x8*)&ps[c0] = ov;
  }
}

// ---------------------------------------------------------------------------
// y fp32 -> ybf (row-major bf16) AND yTb (per-batch transposed bf16), 1 read
__global__ __launch_bounds__(256)
void cvt_yT_k(const float* __restrict__ y, short* __restrict__ ybf,
              short* __restrict__ yTb)
{
  __shared__ float tile[32][33];
  const int tx = threadIdx.x & 31, ty = threadIdx.x >> 5;
  const int h0 = blockIdx.x * 32, t0 = blockIdx.y * 32;
  const float* ip = y + (long long)blockIdx.z * 2048 * 1024;
  short* op  = ybf + (long long)blockIdx.z * 2048 * 1024;
  short* opT = yTb + (long long)blockIdx.z * 1024 * 2048;
#pragma unroll
  for (int i = 0; i < 4; ++i) {
    const float f = ip[(long long)(t0 + ty + 8 * i) * 1024 + h0 + tx];
    tile[ty + 8 * i][tx] = f;
    op[(long long)(t0 + ty + 8 * i) * 1024 + h0 + tx] = f2bf(f);
  }
  __syncthreads();
#pragma unroll
  for (int i = 0; i < 4; ++i)
    opT[(long long)(h0 + ty + 8 * i) * 2048 + t0 + tx] = f2bf(tile[tx][ty + 8 * i]);
}

// z=0,1,2: W -> W^T bf16 (Wq,Wk,Wo); z=3: Wv -> plain bf16 (no transpose)
__global__ __launch_bounds__(256)
void cvt_w_all_k(const float* __restrict__ w0, const float* __restrict__ w1,
                 const float* __restrict__ w2, const float* __restrict__ w3,
                 short* __restrict__ o0, short* __restrict__ o1,
                 short* __restrict__ o2, short* __restrict__ o3)
{
  const int tx = threadIdx.x & 31, ty = threadIdx.x >> 5;
  const int r0 = blockIdx.y * 32, c0 = blockIdx.x * 32;
  if (blockIdx.z == 3) {          // plain convert
#pragma unroll
    for (int i = 0; i < 4; ++i)
      o3[(long long)(r0 + ty + 8 * i) * 1024 + c0 + tx] =
          f2bf(w3[(long long)(r0 + ty + 8 * i) * 1024 + c0 + tx]);
    return;
  }
  const float* in = (blockIdx.z == 0) ? w0 : (blockIdx.z == 1 ? w1 : w2);
  short* out      = (blockIdx.z == 0) ? o0 : (blockIdx.z == 1 ? o1 : o2);
  __shared__ float tile[32][33];
#pragma unroll
  for (int i = 0; i < 4; ++i)
    tile[ty + 8 * i][tx] = in[(long long)(r0 + ty + 8 * i) * 1024 + c0 + tx];
  __syncthreads();
#pragma unroll
  for (int i = 0; i < 4; ++i)
    out[(long long)(c0 + ty + 8 * i) * 1024 + r0 + tx] = f2bf(tile[tx][ty + 8 * i]);
}

// outb[j] = bo[j]
__global__ __launch_bounds__(256)
void bias_init_k(const float* __restrict__ bo, float* __restrict__ outb)
{
  const int j = blockIdx.x * 256 + threadIdx.x;
  outb[j] = bo[j];
}

// outb[j] += sum over 16 rows of bv[r]*Wo[r][j]
__global__ __launch_bounds__(256)
void bias_fold_k(const float* __restrict__ bv, const float* __restrict__ Wo,
                 float* __restrict__ outb)
{
  const int r0 = blockIdx.x * 16;
  const int c4 = threadIdx.x;
  float4 acc = make_float4(0.f, 0.f, 0.f, 0.f);
  for (int r = 0; r < 16; ++r) {
    const float s = bv[r0 + r];
    const float4 w = ((const float4*)(Wo + (long long)(r0 + r) * 1024))[c4];
    acc.x += s * w.x; acc.y += s * w.y; acc.z += s * w.z; acc.w += s * w.w;
  }
  atomicAdd(&outb[c4 * 4 + 0], acc.x);
  atomicAdd(&outb[c4 * 4 + 1], acc.y);
  atomicAdd(&outb[c4 * 4 + 2], acc.z);
  atomicAdd(&outb[c4 * 4 + 3], acc.w);
}

// WvoT = bf16( part0 + part1 + part2 + part3 )  (split-K combine, 1M elems)
__global__ __launch_bounds__(256)
void combine4_k(const float* __restrict__ p, short* __restrict__ out)
{
  const long long i = (long long)blockIdx.x * 256 + threadIdx.x;  // float4 idx
  const float4 a = ((const float4*)p)[i];
  const float4 b = ((const float4*)(p + 1048576))[i];
  const float4 c = ((const float4*)(p + 2097152))[i];
  const float4 d = ((const float4*)(p + 3145728))[i];
  bf16x4 o;
  o[0] = f2bf(a.x + b.x + c.x + d.x);
  o[1] = f2bf(a.y + b.y + c.y + d.y);
  o[2] = f2bf(a.z + b.z + c.z + d.z);
  o[3] = f2bf(a.w + b.w + c.w + d.w);
  ((bf16x4*)out)[i] = o;
}

// ---------------------------------------------------------------------------
extern "C" void kernel_launch(void* const* d_in, const int* in_sizes, int n_in,
                              void* d_out, int out_size, void* d_ws, size_t ws_size,
                              hipStream_t stream)
{
  (void)in_sizes; (void)n_in; (void)out_size; (void)ws_size;
  const float* y  = (const float*)d_in[0];
  const float* Wq = (const float*)d_in[1];
  const float* bq = (const float*)d_in[2];
  const float* Wk = (const float*)d_in[3];
  const float* bk = (const float*)d_in[4];
  const float* Wv = (const float*)d_in[5];
  const float* bv = (const float*)d_in[6];
  const float* Wo = (const float*)d_in[7];
  const float* bo = (const float*)d_in[8];
  float* out = (float*)d_out;

  const int T = 2048, H = 1024, DK = 1024;
  const long long MT = 8192;                          // B*T

  // workspace layout (shorts); ~128 MB
  short* ws    = (short*)d_ws;
  short* ybf   = ws;                                  // MT*1024
  short* WqkT  = ybf + MT * H;                        // 2*1024*1024
  short* WoT   = WqkT + 2ll * 1024 * 1024;            // 1024*1024
  short* WvBf  = WoT + 1024ll * 1024;                 // 1024*1024
  short* WvoT  = WvBf + 1024ll * 1024;                // 1024*1024 ((Wv@Wo)^T)
  short* QKb   = WvoT + 1024ll * 1024;                // MT*2048 (Q | K)
  short* yTb   = QKb + MT * 2048;                     // 4 x 1024 x 2048
  short* scores = yTb + MT * 1024;                    // 4*T*T bf16
  float* bvWoBo = (float*)(scores + 4ll * T * T);     // 1024 fp32
  float* wvoPart = bvWoBo + 1024;                     // 4 x 1M fp32 (16MB)
  short* ctxY  = ybf;                                 // reuse (ybf dead by PY)

  // 1. conversions (y read once; all weights in one dispatch) + bias fold
  cvt_yT_k<<<dim3(32, 64, 4), 256, 0, stream>>>(y, ybf, yTb);
  cvt_w_all_k<<<dim3(32, 32, 4), 256, 0, stream>>>(
      Wq, Wk, Wo, Wv, WqkT, WqkT + 1024ll * 1024, WoT, WvBf);
  bias_init_k<<<4, 256, 0, stream>>>(bo, bvWoBo);
  bias_fold_k<<<64, 256, 0, stream>>>(bv, Wo, bvWoBo);

  // 2. WvoT = (Wv@Wo)^T via A=WoT, B=WvBf — split-K x4 (z = k-quarter),
  //    fp32 partials, then combine to bf16.
  gemm_bt<0, 0, true, 0><<<dim3(64, 1, 4), 256, 0, stream>>>(
      WoT, WvBf, wvoPart, nullptr, 1.f, 256, 1024, 1024, 1024,
      256, 256, 1048576, 8);
  combine4_k<<<1024, 256, 0, stream>>>(wvoPart, WvoT);

  // 3. fused QK projection (merged-phase 256^2, grid 256 = 1 block/CU)
  gemm_qkproj_8ph<<<dim3(32 * 8, 1, 1), 512, 0, stream>>>(
      ybf, WqkT, QKb, bq, bk, 1.f / 32.f, H, H, H, 2048, 8);

  // 4. scores = Q @ K^T -> bf16, causal tile skip (BK=64)
  gemm_bt<1, 0, false, 0><<<dim3(16 * 16, 1, 4), 256, 0, stream>>>(
      QKb, QKb + 1024, scores, nullptr, 1.f, DK, 2048, 2048, T,
      (long long)T * 2048, (long long)T * 2048, (long long)T * T, 16);

  // 5. causal softmax in place (trimmed to live columns)
  softmax_causal_bf16_k<<<(int)MT, 256, 0, stream>>>(scores);

  // 6. ctxY = P @ y  (B = yTb per batch; heavy-first; BK=64)
  gemm_bt<2, 0, false, 2><<<dim3(16 * 8, 1, 4), 256, 0, stream>>>(
      scores, yTb, ctxY, nullptr, 1.f, T, T, 2048, 1024,
      (long long)T * T, 1024ll * 2048, (long long)T * 1024, 8);

  // 7. out = ctxY @ (Wv@Wo) + (bv@Wo + bo)
  gemm_bt<0, 1, true, 0><<<dim3(64 * 8, 1, 1), 256, 0, stream>>>(
      ctxY, WvoT, out, bvWoBo, 1.f, 1024, 1024, 1024, 1024, 0, 0, 0, 8);
}

// Round 2
// 190.941 us; speedup vs baseline: 1.0262x; 1.0201x over previous
//
#include <hip/hip_runtime.h>
#include <hip/hip_bf16.h>
#include <cstdint>

#define DEVI __device__ __forceinline__

typedef __attribute__((ext_vector_type(8))) short bf16x8;
typedef __attribute__((ext_vector_type(4))) short bf16x4;
typedef __attribute__((ext_vector_type(4))) float f32x4;

template<int I> struct IC { static constexpr int v = I; };

DEVI short f2bf(float f) {
  unsigned u = __float_as_uint(f);
  u += 0x7fff + ((u >> 16) & 1);   // round-to-nearest-even
  return (short)(u >> 16);
}
DEVI float bf2f(short s) { return __uint_as_float(((unsigned)(unsigned short)s) << 16); }

DEVI void gl_lds16(const short* g, short* l) {
  __builtin_amdgcn_global_load_lds((const __attribute__((address_space(1))) unsigned*)g,
                                   (__attribute__((address_space(3))) unsigned*)l, 16, 0, 0);
}

DEVI void bar() {
  asm volatile("" ::: "memory");
  __builtin_amdgcn_s_barrier();
  asm volatile("" ::: "memory");
}

// ===========================================================================
// 256x256 GEMM: QK projection. R17 merged 2-phase (neutral vs 4-phase, kept:
// fewer barriers). R18 note: per-K-step 8640cy vs 3300cy at 4k^3 with same
// code — NOT barrier-bound; left as-is this round.
// ===========================================================================
__global__ __launch_bounds__(512, 1)
void gemm_qkproj_8ph(const short* __restrict__ A, const short* __restrict__ B,
                     short* __restrict__ C, const float* __restrict__ b0,
                     const float* __restrict__ b1, float scale,
                     int K, int lda, int ldb, int ldc, int tilesN)
{
  const int nwg = gridDim.x, orig = blockIdx.x;
  const int q8 = nwg >> 3, r8 = nwg & 7;
  const int xcd = orig & 7, idx8 = orig >> 3;
  const int wg = (xcd < r8 ? xcd * (q8 + 1) : r8 * (q8 + 1) + (xcd - r8) * q8) + idx8;
  const int bi = wg / tilesN, bj = wg - bi * tilesN;

  __shared__ __align__(16) short lA[4][8192];
  __shared__ __align__(16) short lB[4][8192];

  const int tid = threadIdx.x, wave = tid >> 6, lane = tid & 63;
  const int wm = wave >> 2, wn = wave & 3;
  const int fr = lane & 15, h = lane >> 4;
  const int brow = bi * 256, bcol = bj * 256;

  const int ck = (h ^ ((fr >> 1) & 3)) * 8;
  const int aBase = (wm * 128 + fr) * 32 + ck;
  const int bBase = (wn * 64 + fr) * 32 + ck;

  const int swc = ((tid & 3) ^ ((tid >> 3) & 3)) * 8;
  const short* pa = A + (long long)(brow + (tid >> 2)) * lda + swc;
  const short* pb = B + (long long)(bcol + (tid >> 2)) * ldb + swc;

  f32x4 acc[8][4] = {};
  const int nt = K / 64;

  auto stgA = [&](auto SL, int koff) {
    constexpr int s = decltype(SL)::v;
    gl_lds16(pa + koff,                  &lA[s][tid * 8]);
    gl_lds16(pa + koff + 128 * (long long)lda, &lA[s][4096 + tid * 8]);
  };
  auto stgB = [&](auto SL, int koff) {
    constexpr int s = decltype(SL)::v;
    gl_lds16(pb + koff,                  &lB[s][tid * 8]);
    gl_lds16(pb + koff + 128 * (long long)ldb, &lB[s][4096 + tid * 8]);
  };

  stgA(IC<0>{}, 0);   stgB(IC<0>{}, 0);
  stgA(IC<1>{}, 32);  stgB(IC<1>{}, 32);
  stgA(IC<2>{}, 64);  stgB(IC<2>{}, 64);
  stgA(IC<3>{}, 96);
  asm volatile("s_waitcnt vmcnt(6)" ::: "memory");
  bar();

  auto group = [&](auto PC, int t) {
    constexpr int P  = decltype(PC)::v;
    constexpr int s0 = 2 * P, s1 = 2 * P + 1;
    constexpr int ob1 = 2 * (P ^ 1) + 1;
    const bool st1 = (t + 1 < nt), st2 = (t + 2 < nt);
    const int k2 = (t + 2) * 64;
    bf16x8 a[4], a2[4], b[4];

    // ---- merged phase A: K-half s0, both M-quadrants (32 MFMA) ----
#pragma unroll
    for (int m = 0; m < 4; ++m) a[m]  = *(const bf16x8*)&lA[s0][aBase + (m * 16) * 32];
#pragma unroll
    for (int m = 0; m < 4; ++m) a2[m] = *(const bf16x8*)&lA[s0][aBase + (64 + m * 16) * 32];
#pragma unroll
    for (int n = 0; n < 4; ++n) b[n]  = *(const bf16x8*)&lB[s0][bBase + (n * 16) * 32];
    if (st1) stgB(IC<ob1>{}, (t + 1) * 64 + 32);
    if (st2) stgA(IC<s0>{}, k2);
    bar();
    asm volatile("s_waitcnt lgkmcnt(0)" ::: "memory");
    __builtin_amdgcn_sched_barrier(0);
    __builtin_amdgcn_s_setprio(1);
#pragma unroll
    for (int m = 0; m < 4; ++m)
#pragma unroll
      for (int n = 0; n < 4; ++n)
        acc[m][n] = __builtin_amdgcn_mfma_f32_16x16x32_bf16(a[m], b[n], acc[m][n], 0, 0, 0);
#pragma unroll
    for (int m = 0; m < 4; ++m)
#pragma unroll
      for (int n = 0; n < 4; ++n)
        acc[m + 4][n] = __builtin_amdgcn_mfma_f32_16x16x32_bf16(a2[m], b[n], acc[m + 4][n], 0, 0, 0);
    __builtin_amdgcn_s_setprio(0);
    bar();

    // ---- merged phase B: K-half s1, both M-quadrants (32 MFMA) ----
#pragma unroll
    for (int m = 0; m < 4; ++m) a[m]  = *(const bf16x8*)&lA[s1][aBase + (m * 16) * 32];
#pragma unroll
    for (int m = 0; m < 4; ++m) a2[m] = *(const bf16x8*)&lA[s1][aBase + (64 + m * 16) * 32];
#pragma unroll
    for (int n = 0; n < 4; ++n) b[n]  = *(const bf16x8*)&lB[s1][bBase + (n * 16) * 32];
    if (st2) { stgB(IC<s0>{}, k2); stgA(IC<s1>{}, k2 + 32); }
    bar();
    asm volatile("s_waitcnt lgkmcnt(0)" ::: "memory");
    __builtin_amdgcn_sched_barrier(0);
    __builtin_amdgcn_s_setprio(1);
#pragma unroll
    for (int m = 0; m < 4; ++m)
#pragma unroll
      for (int n = 0; n < 4; ++n)
        acc[m][n] = __builtin_amdgcn_mfma_f32_16x16x32_bf16(a[m], b[n], acc[m][n], 0, 0, 0);
#pragma unroll
    for (int m = 0; m < 4; ++m)
#pragma unroll
      for (int n = 0; n < 4; ++n)
        acc[m + 4][n] = __builtin_amdgcn_mfma_f32_16x16x32_bf16(a2[m], b[n], acc[m + 4][n], 0, 0, 0);
    __builtin_amdgcn_s_setprio(0);
    if (st2)      asm volatile("s_waitcnt vmcnt(6)" ::: "memory");
    else if (st1) asm volatile("s_waitcnt vmcnt(0)" ::: "memory");
    if (st1) bar();
  };

  for (int t = 0; t + 1 < nt; t += 2) { group(IC<0>{}, t); group(IC<1>{}, t + 1); }

  // epilogue, n-INNERMOST: each 64B line completed within 4 consecutive stores
  int   colg[4]; float bvv[4], scl[4];
#pragma unroll
  for (int n = 0; n < 4; ++n) {
    colg[n] = bcol + wn * 64 + n * 16 + fr;
    const int seg = colg[n] >> 10;
    bvv[n] = seg ? b1[colg[n] & 1023] : b0[colg[n] & 1023];
    scl[n] = seg ? 1.f : scale;
  }
#pragma unroll
  for (int m = 0; m < 8; ++m) {
    const int row = brow + wm * 128 + m * 16 + h * 4;
#pragma unroll
    for (int j = 0; j < 4; ++j) {
      short* cr = C + (long long)(row + j) * ldc;
#pragma unroll
      for (int n = 0; n < 4; ++n)
        cr[colg[n]] = f2bf((acc[m][n][j] + bvv[n]) * scl[n]);
    }
  }
}

// ===========================================================================
// 128x128 GEMM, BK=64. R18 changes:
//   MODE 4: triangular decode — grid holds ONLY the 136 live causal tiles
//     (L -> (bi,bj) via isqrt). Old MODE 1 parked ~120 dead wgs per z on the
//     same-x CUs for all 4 z => ~47% of CUs idle for the whole dispatch.
//   DECODE 3: z-pairing balance for PV. Grid 512 = all-resident (2/CU, no
//     queue) and dispatch pairs (z,x) with (z+2,x) on one CU => same bi twice
//     (heavy CU = 64 BK-steps vs mean 34). Complement bi when (z&2) => every
//     CU pair is (bi, 15-bi) = uniform 34 steps.
// MODE 0 plain / 2 causal-PV (kend=(bi+1)*128) / 4 triangular.
// BIASMODE 0 none / 1 col fp32.
// ===========================================================================
constexpr int BM = 128, BN = 128, BK = 64;

template<int MODE, int BIASMODE, bool OUTF32, int DECODE>
__global__ __launch_bounds__(256, 2)
void gemm_bt(const short* __restrict__ A, const short* __restrict__ B,
             void* __restrict__ Cv, const float* __restrict__ b0,
             float scale, int K, int lda, int ldb, int ldc,
             long long sA, long long sB, long long sC, int tdim)
{
  const int nwg = gridDim.x, orig = blockIdx.x;
  const int q8 = nwg >> 3, r8 = nwg & 7;
  const int xcd = orig & 7, idx8 = orig >> 3;
  const int wg = (xcd < r8 ? xcd * (q8 + 1) : r8 * (q8 + 1) + (xcd - r8) * q8) + idx8;
  const int bz = blockIdx.z;

  int bi, bj;
  if constexpr (MODE == 4) {
    // triangular decode: wg = bi*(bi+1)/2 + bj, bj <= bi
    int b = (int)((__fsqrt_rn(8.f * (float)wg + 1.f) - 1.f) * 0.5f);
    if ((b + 1) * (b + 2) / 2 <= wg) ++b;          // float-edge fixup
    if (b * (b + 1) / 2 > wg) --b;
    bi = b; bj = wg - b * (b + 1) / 2;
  } else {
    bi = wg / tdim;
    bj = wg - bi * tdim;
    if constexpr (DECODE == 2) bi = (nwg / tdim) - 1 - bi;          // heavy-first
    if constexpr (DECODE == 3) { if (bz & 2) bi = (nwg / tdim) - 1 - bi; }
  }

  A += (long long)bz * sA;
  B += (long long)bz * sB;

  __shared__ __align__(16) short lA[2][BM * BK];   // 2 x 16 KB
  __shared__ __align__(16) short lB[2][BN * BK];   // 2 x 16 KB

  const int tid = threadIdx.x, wave = tid >> 6, lane = tid & 63;
  const int wr = wave >> 1, wc = wave & 1;
  const int brow = bi * BM, bcol = bj * BN;
  const int fr = lane & 15, h = lane >> 4;

  const int ck0 = ((h ^ (fr & 7))) * 8;            // 128B-row swizzle, ks=0
  const int swc = ((tid & 7) ^ ((tid >> 3) & 7)) * 8;
  const short* pA = A + (long long)(brow + (tid >> 3)) * lda + swc;
  const short* pB = B + (long long)(bcol + (tid >> 3)) * ldb + swc;

  f32x4 acc[4][4] = {};
  const int kend = (MODE == 2) ? (bi + 1) * BM : K;
  const int nt = kend / BK;

  auto stage = [&](int buf, int t) {
    const long long ko = (long long)t * BK;
#pragma unroll
    for (int j = 0; j < 4; ++j)
      gl_lds16(pA + (long long)(j * 32) * lda + ko, &lA[buf][j * 2048 + tid * 8]);
#pragma unroll
    for (int j = 0; j < 4; ++j)
      gl_lds16(pB + (long long)(j * 32) * ldb + ko, &lB[buf][j * 2048 + tid * 8]);
  };

  stage(0, 0);
  __syncthreads();

  int cur = 0;
  for (int t = 0; t < nt; ++t) {
    if (t + 1 < nt) stage(cur ^ 1, t + 1);

    const short* bufA = lA[cur];
    const short* bufB = lB[cur];
    bf16x8 af[4], bg[4];
#pragma unroll
    for (int m = 0; m < 4; ++m)
      af[m] = *(const bf16x8*)&bufA[(wr * 64 + m * 16 + fr) * BK + ck0];
#pragma unroll
    for (int n = 0; n < 4; ++n)
      bg[n] = *(const bf16x8*)&bufB[(wc * 64 + n * 16 + fr) * BK + ck0];
#pragma unroll
    for (int m = 0; m < 4; ++m)
#pragma unroll
      for (int n = 0; n < 4; ++n)
        acc[m][n] = __builtin_amdgcn_mfma_f32_16x16x32_bf16(af[m], bg[n], acc[m][n], 0, 0, 0);
#pragma unroll
    for (int m = 0; m < 4; ++m)
      af[m] = *(const bf16x8*)&bufA[((wr * 64 + m * 16 + fr) * BK + ck0) ^ 32];
#pragma unroll
    for (int n = 0; n < 4; ++n)
      bg[n] = *(const bf16x8*)&bufB[((wc * 64 + n * 16 + fr) * BK + ck0) ^ 32];
#pragma unroll
    for (int m = 0; m < 4; ++m)
#pragma unroll
      for (int n = 0; n < 4; ++n)
        acc[m][n] = __builtin_amdgcn_mfma_f32_16x16x32_bf16(af[m], bg[n], acc[m][n], 0, 0, 0);

    __syncthreads();
    cur ^= 1;
  }

  // epilogue, n-innermost
  const int lrow = h * 4;
  float* Cf = (float*)Cv + (long long)bz * sC;
  short* Cs = (short*)Cv + (long long)bz * sC;
  int colg[4]; float bvv[4];
#pragma unroll
  for (int n = 0; n < 4; ++n) {
    colg[n] = bcol + wc * 64 + n * 16 + fr;
    bvv[n] = (BIASMODE == 1) ? b0[colg[n]] : 0.f;
  }
#pragma unroll
  for (int m = 0; m < 4; ++m) {
    const int row = brow + wr * 64 + m * 16 + lrow;
#pragma unroll
    for (int j = 0; j < 4; ++j) {
#pragma unroll
      for (int n = 0; n < 4; ++n) {
        const float val = (acc[m][n][j] + bvv[n]) * scale;
        if constexpr (OUTF32) Cf[(long long)(row + j) * ldc + colg[n]] = val;
        else                  Cs[(long long)(row + j) * ldc + colg[n]] = f2bf(val);
      }
    }
  }
}

// ---------------------------------------------------------------------------
// Causal-trimmed softmax: row t has t+1 live cols; load only chunks c0<=t,
// store only c0<roundup128(t+1) (keeps required zeros in the diagonal tile).
__global__ __launch_bounds__(256)
void softmax_causal_bf16_k(short* __restrict__ sc)
{
  const int T = 2048;
  const long long row = blockIdx.x;
  const int t = (int)(row & (T - 1));
  short* ps = sc + row * (long long)T;
  const int tid = threadIdx.x, wave = tid >> 6, lane = tid & 63;
  const int c0 = tid * 8;
  const int wlim = ((t >> 7) + 1) << 7;   // exclusive write limit, 128-aligned

  bf16x8 v = {};
  if (c0 <= t) v = *(const bf16x8*)&ps[c0];
  float x[8];
#pragma unroll
  for (int j = 0; j < 8; ++j) x[j] = bf2f(v[j]);

  float mx = -3.0e38f;
#pragma unroll
  for (int j = 0; j < 8; ++j) if (c0 + j <= t) mx = fmaxf(mx, x[j]);
#pragma unroll
  for (int o = 32; o; o >>= 1) mx = fmaxf(mx, __shfl_xor(mx, o, 64));
  __shared__ float red[8];
  if (lane == 0) red[wave] = mx;
  __syncthreads();
  const float M = fmaxf(fmaxf(red[0], red[1]), fmaxf(red[2], red[3]));

  float e[8], s = 0.f;
#pragma unroll
  for (int j = 0; j < 8; ++j) { e[j] = (c0 + j <= t) ? __expf(x[j] - M) : 0.f; s += e[j]; }
#pragma unroll
  for (int o = 32; o; o >>= 1) s += __shfl_xor(s, o, 64);
  if (lane == 0) red[4 + wave] = s;
  __syncthreads();
  const float inv = 1.f / (red[4] + red[5] + red[6] + red[7]);

  if (c0 < wlim) {
    bf16x8 ov;
#pragma unroll
    for (int j = 0; j < 8; ++j) ov[j] = f2bf(e[j] * inv);
    *(bf16x8*)&ps[c0] = ov;
  }
}

// ---------------------------------------------------------------------------
// y fp32 -> ybf (row-major bf16) AND yTb (per-batch transposed bf16), 1 read
__global__ __launch_bounds__(256)
void cvt_yT_k(const float* __restrict__ y, short* __restrict__ ybf,
              short* __restrict__ yTb)
{
  __shared__ float tile[32][33];
  const int tx = threadIdx.x & 31, ty = threadIdx.x >> 5;
  const int h0 = blockIdx.x * 32, t0 = blockIdx.y * 32;
  const float* ip = y + (long long)blockIdx.z * 2048 * 1024;
  short* op  = ybf + (long long)blockIdx.z * 2048 * 1024;
  short* opT = yTb + (long long)blockIdx.z * 1024 * 2048;
#pragma unroll
  for (int i = 0; i < 4; ++i) {
    const float f = ip[(long long)(t0 + ty + 8 * i) * 1024 + h0 + tx];
    tile[ty + 8 * i][tx] = f;
    op[(long long)(t0 + ty + 8 * i) * 1024 + h0 + tx] = f2bf(f);
  }
  __syncthreads();
#pragma unroll
  for (int i = 0; i < 4; ++i)
    opT[(long long)(h0 + ty + 8 * i) * 2048 + t0 + tx] = f2bf(tile[tx][ty + 8 * i]);
}

// z=0,1,2: W -> W^T bf16 (Wq,Wk,Wo); z=3: Wv -> plain bf16 (no transpose)
__global__ __launch_bounds__(256)
void cvt_w_all_k(const float* __restrict__ w0, const float* __restrict__ w1,
                 const float* __restrict__ w2, const float* __restrict__ w3,
                 short* __restrict__ o0, short* __restrict__ o1,
                 short* __restrict__ o2, short* __restrict__ o3)
{
  const int tx = threadIdx.x & 31, ty = threadIdx.x >> 5;
  const int r0 = blockIdx.y * 32, c0 = blockIdx.x * 32;
  if (blockIdx.z == 3) {          // plain convert
#pragma unroll
    for (int i = 0; i < 4; ++i)
      o3[(long long)(r0 + ty + 8 * i) * 1024 + c0 + tx] =
          f2bf(w3[(long long)(r0 + ty + 8 * i) * 1024 + c0 + tx]);
    return;
  }
  const float* in = (blockIdx.z == 0) ? w0 : (blockIdx.z == 1 ? w1 : w2);
  short* out      = (blockIdx.z == 0) ? o0 : (blockIdx.z == 1 ? o1 : o2);
  __shared__ float tile[32][33];
#pragma unroll
  for (int i = 0; i < 4; ++i)
    tile[ty + 8 * i][tx] = in[(long long)(r0 + ty + 8 * i) * 1024 + c0 + tx];
  __syncthreads();
#pragma unroll
  for (int i = 0; i < 4; ++i)
    out[(long long)(c0 + ty + 8 * i) * 1024 + r0 + tx] = f2bf(tile[tx][ty + 8 * i]);
}

// outb[j] = bo[j]
__global__ __launch_bounds__(256)
void bias_init_k(const float* __restrict__ bo, float* __restrict__ outb)
{
  const int j = blockIdx.x * 256 + threadIdx.x;
  outb[j] = bo[j];
}

// outb[j] += sum over 16 rows of bv[r]*Wo[r][j]
__global__ __launch_bounds__(256)
void bias_fold_k(const float* __restrict__ bv, const float* __restrict__ Wo,
                 float* __restrict__ outb)
{
  const int r0 = blockIdx.x * 16;
  const int c4 = threadIdx.x;
  float4 acc = make_float4(0.f, 0.f, 0.f, 0.f);
  for (int r = 0; r < 16; ++r) {
    const float s = bv[r0 + r];
    const float4 w = ((const float4*)(Wo + (long long)(r0 + r) * 1024))[c4];
    acc.x += s * w.x; acc.y += s * w.y; acc.z += s * w.z; acc.w += s * w.w;
  }
  atomicAdd(&outb[c4 * 4 + 0], acc.x);
  atomicAdd(&outb[c4 * 4 + 1], acc.y);
  atomicAdd(&outb[c4 * 4 + 2], acc.z);
  atomicAdd(&outb[c4 * 4 + 3], acc.w);
}

// WvoT = bf16( part0 + part1 + part2 + part3 )  (split-K combine, 1M elems)
__global__ __launch_bounds__(256)
void combine4_k(const float* __restrict__ p, short* __restrict__ out)
{
  const long long i = (long long)blockIdx.x * 256 + threadIdx.x;  // float4 idx
  const float4 a = ((const float4*)p)[i];
  const float4 b = ((const float4*)(p + 1048576))[i];
  const float4 c = ((const float4*)(p + 2097152))[i];
  const float4 d = ((const float4*)(p + 3145728))[i];
  bf16x4 o;
  o[0] = f2bf(a.x + b.x + c.x + d.x);
  o[1] = f2bf(a.y + b.y + c.y + d.y);
  o[2] = f2bf(a.z + b.z + c.z + d.z);
  o[3] = f2bf(a.w + b.w + c.w + d.w);
  ((bf16x4*)out)[i] = o;
}

// ---------------------------------------------------------------------------
extern "C" void kernel_launch(void* const* d_in, const int* in_sizes, int n_in,
                              void* d_out, int out_size, void* d_ws, size_t ws_size,
                              hipStream_t stream)
{
  (void)in_sizes; (void)n_in; (void)out_size; (void)ws_size;
  const float* y  = (const float*)d_in[0];
  const float* Wq = (const float*)d_in[1];
  const float* bq = (const float*)d_in[2];
  const float* Wk = (const float*)d_in[3];
  const float* bk = (const float*)d_in[4];
  const float* Wv = (const float*)d_in[5];
  const float* bv = (const float*)d_in[6];
  const float* Wo = (const float*)d_in[7];
  const float* bo = (const float*)d_in[8];
  float* out = (float*)d_out;

  const int T = 2048, H = 1024, DK = 1024;
  const long long MT = 8192;                          // B*T

  // workspace layout (shorts); ~128 MB
  short* ws    = (short*)d_ws;
  short* ybf   = ws;                                  // MT*1024
  short* WqkT  = ybf + MT * H;                        // 2*1024*1024
  short* WoT   = WqkT + 2ll * 1024 * 1024;            // 1024*1024
  short* WvBf  = WoT + 1024ll * 1024;                 // 1024*1024
  short* WvoT  = WvBf + 1024ll * 1024;                // 1024*1024 ((Wv@Wo)^T)
  short* QKb   = WvoT + 1024ll * 1024;                // MT*2048 (Q | K)
  short* yTb   = QKb + MT * 2048;                     // 4 x 1024 x 2048
  short* scores = yTb + MT * 1024;                    // 4*T*T bf16
  float* bvWoBo = (float*)(scores + 4ll * T * T);     // 1024 fp32
  float* wvoPart = bvWoBo + 1024;                     // 4 x 1M fp32 (16MB)
  short* ctxY  = ybf;                                 // reuse (ybf dead by PY)

  // 1. conversions (y read once; all weights in one dispatch) + bias fold
  cvt_yT_k<<<dim3(32, 64, 4), 256, 0, stream>>>(y, ybf, yTb);
  cvt_w_all_k<<<dim3(32, 32, 4), 256, 0, stream>>>(
      Wq, Wk, Wo, Wv, WqkT, WqkT + 1024ll * 1024, WoT, WvBf);
  bias_init_k<<<4, 256, 0, stream>>>(bo, bvWoBo);
  bias_fold_k<<<64, 256, 0, stream>>>(bv, Wo, bvWoBo);

  // 2. WvoT = (Wv@Wo)^T via A=WoT, B=WvBf — split-K x4 (z = k-quarter),
  //    fp32 partials, then combine to bf16.
  gemm_bt<0, 0, true, 0><<<dim3(64, 1, 4), 256, 0, stream>>>(
      WoT, WvBf, wvoPart, nullptr, 1.f, 256, 1024, 1024, 1024,
      256, 256, 1048576, 8);
  combine4_k<<<1024, 256, 0, stream>>>(wvoPart, WvoT);

  // 3. fused QK projection (merged-phase 256^2, grid 256 = 1 block/CU)
  gemm_qkproj_8ph<<<dim3(32 * 8, 1, 1), 512, 0, stream>>>(
      ybf, WqkT, QKb, bq, bk, 1.f / 32.f, H, H, H, 2048, 8);

  // 4. scores = Q @ K^T -> bf16, TRIANGULAR grid: only the 136 live causal
  //    tiles per batch (136 % 8 == 0 -> XCD swizzle bijective)
  gemm_bt<4, 0, false, 0><<<dim3(136, 1, 4), 256, 0, stream>>>(
      QKb, QKb + 1024, scores, nullptr, 1.f, DK, 2048, 2048, T,
      (long long)T * 2048, (long long)T * 2048, (long long)T * T, 16);

  // 5. causal softmax in place (trimmed to live columns)
  softmax_causal_bf16_k<<<(int)MT, 256, 0, stream>>>(scores);

  // 6. ctxY = P @ y  (B = yTb per batch; z-complement pairing balance; BK=64)
  gemm_bt<2, 0, false, 3><<<dim3(16 * 8, 1, 4), 256, 0, stream>>>(
      scores, yTb, ctxY, nullptr, 1.f, T, T, 2048, 1024,
      (long long)T * T, 1024ll * 2048, (long long)T * 1024, 8);

  // 7. out = ctxY @ (Wv@Wo) + (bv@Wo + bo)
  gemm_bt<0, 1, true, 0><<<dim3(64 * 8, 1, 1), 256, 0, stream>>>(
      ctxY, WvoT, out, bvWoBo, 1.f, 1024, 1024, 1024, 1024, 0, 0, 0, 8);
}